// Round 3
// baseline (40.771 us; speedup 1.0000x reference)
//
#include <hip/hip_runtime.h>
#include <hip/hip_bf16.h>

#define BATCH 4
#define NB    256
#define NE    (NB*(NB-1))   // 65280

typedef short    short8 __attribute__((ext_vector_type(8)));
typedef float    f32x16 __attribute__((ext_vector_type(16)));
typedef unsigned u32x4  __attribute__((ext_vector_type(4)));

__device__ __forceinline__ short f2bf(float x) {
    return __builtin_bit_cast(short, __float2bfloat16(x));   // RNE
}
__device__ __forceinline__ unsigned pk2(float lo, float hi) {
    return (unsigned)(unsigned short)f2bf(lo) |
           ((unsigned)(unsigned short)f2bf(hi) << 16);
}
// v_permlane32_swap_b32: a.upper32lanes <-> b.lower32lanes
__device__ __forceinline__ void pl32swap(unsigned& a, unsigned& b) {
    asm volatile("v_permlane32_swap_b32 %0, %1" : "+v"(a), "+v"(b));
}

// A1 fragments for swapped GEMM1: lane holds W1[i][f=16k0+8lh+j][h=l31+32ht]
__device__ __forceinline__ void loadA1(const float* __restrict__ W1i,
                                       int l31, int lh, short8 a1f[2][4]) {
    #pragma unroll
    for (int ht = 0; ht < 2; ++ht)
        #pragma unroll
        for (int k0 = 0; k0 < 4; ++k0) {
            const int h  = l31 + 32 * ht;
            const int fb = 16 * k0 + 8 * lh;
            short8 v;
            #pragma unroll
            for (int j = 0; j < 8; ++j) v[j] = f2bf(W1i[(fb + j) * 64 + h]);
            a1f[ht][k0] = v;
        }
}

// ---------------------------------------------------------------------------
// Single fused kernel: one workgroup per (b, receiver r); 256 threads = 4 waves.
// Per wg: stage x[b] as swizzled bf16 LDS + W2 frags + rt + q-row, then
// GEMM1 (swapped, W1T@xsT) -> in-register repack -> GEMM2 (msg1@W2) ->
// weighted row-reduce -> fused output MLP -> residual write.
// ---------------------------------------------------------------------------
__global__ __launch_bounds__(256, 3) void fused_kernel(
    const float* __restrict__ x,        // [B][N][64]
    const float* __restrict__ rel_type, // [B][E][2]
    const float* __restrict__ W1,       // [2][128][64]
    const float* __restrict__ b1,       // [2][64]
    const float* __restrict__ W2,       // [2][64][64]
    const float* __restrict__ b2,       // [2][64]
    const float* __restrict__ Wo1,      // [128][64]
    const float* __restrict__ bo1,      // [64]
    const float* __restrict__ Wo2,      // [64][64]
    const float* __restrict__ bo2,      // [64]
    float* __restrict__ out)
{
    const int b    = blockIdx.x >> 8;
    const int r    = blockIdx.x & 255;
    const int t    = threadIdx.x;
    const int lane = t & 63;
    const int w    = t >> 6;
    const int l31  = lane & 31;
    const int lh   = lane >> 5;

    __shared__ __align__(16) short xbf[NB * 64];   // 32 KiB, XOR-swizzled [n][f]
    __shared__ __align__(16) short W2l[8192];      // 16 KiB B-fragments
    __shared__ __align__(16) float rt2[2][256];    // 2 KiB
    __shared__ __align__(16) float qrow[2][64];    // 512 B
    __shared__ __align__(16) float red[4][64];     // 1 KiB
    __shared__ __align__(16) float xl[64];
    __shared__ __align__(16) float aggl[64];
    __shared__ __align__(16) float predl[64];

    // ---- phase A: A1 prefetch (type 0) + x->bf16 staging + rt + xl ----
    short8 a1f[2][4];
    loadA1(W1, l31, lh, a1f);

    const float* xb = x + (size_t)b * NB * 64;
    #pragma unroll
    for (int rep = 0; rep < 4; ++rep) {
        const int n  = (t >> 2) + 64 * rep;
        const int f0 = (t & 3) * 16;
        float4 v0 = *(const float4*)(xb + n * 64 + f0);
        float4 v1 = *(const float4*)(xb + n * 64 + f0 + 4);
        float4 v2 = *(const float4*)(xb + n * 64 + f0 + 8);
        float4 v3 = *(const float4*)(xb + n * 64 + f0 + 12);
        short8 s0 = { f2bf(v0.x), f2bf(v0.y), f2bf(v0.z), f2bf(v0.w),
                      f2bf(v1.x), f2bf(v1.y), f2bf(v1.z), f2bf(v1.w) };
        short8 s1 = { f2bf(v2.x), f2bf(v2.y), f2bf(v2.z), f2bf(v2.w),
                      f2bf(v3.x), f2bf(v3.y), f2bf(v3.z), f2bf(v3.w) };
        const int base = n * 128;
        const int sw   = (n & 7) << 4;
        *(short8*)((char*)xbf + (base + ((f0 * 2)      ^ sw))) = s0;
        *(short8*)((char*)xbf + (base + ((f0 * 2 + 16) ^ sw))) = s1;
    }
    if (t < 255) {
        const float* p = rel_type + ((size_t)b * NE + (size_t)r * 255 + t) * 2;
        rt2[0][t] = p[0];
        rt2[1][t] = p[1];
    } else {
        rt2[0][255] = 0.f; rt2[1][255] = 0.f;      // pad edge contributes 0
    }
    if (t >= 192) xl[t - 192] = xb[r * 64 + (t - 192)];
    __syncthreads();

    // ---- phase B: q-row (waves 0-1) | W2 fragment staging (waves 2-3) ----
    if (t < 128) {
        const int i = t >> 6, h = t & 63;
        float acc = b1[i * 64 + h];
        const float* w1r = W1 + i * 8192 + 4096;   // receiver rows 64..127
        #pragma unroll 16
        for (int f = 0; f < 64; ++f) acc = fmaf(xl[f], w1r[f * 64 + h], acc);
        qrow[i][h] = acc;
    } else {
        const int i  = (t >> 6) - 2;
        const int ln = t & 63;
        #pragma unroll
        for (int c = 0; c < 8; ++c) {              // c = nt*4 + k0
            const int nt = c >> 2, k0 = c & 3;
            short8 v;
            #pragma unroll
            for (int j = 0; j < 8; ++j) {
                const int k = 16 * k0 + 8 * (ln >> 5) + j;
                const int n = (ln & 31) + 32 * nt;
                v[j] = f2bf(W2[(i * 64 + k) * 64 + n]);
            }
            *(short8*)(W2l + ((i * 8 + c) * 64 + ln) * 8) = v;
        }
    }
    __syncthreads();

    // ---- B1 fragments: x_bf gather (shared by both edge types) ----
    short8 b1f[2][4];
    #pragma unroll
    for (int et = 0; et < 2; ++et) {
        const int kap = 64 * w + 32 * et + l31;
        int s = (kap < r) ? kap : kap + 1;
        if (s > 255) s = 255;                       // pad row, rt=0
        const int base = s * 128, sw = (s & 7) << 4;
        #pragma unroll
        for (int k0 = 0; k0 < 4; ++k0)
            b1f[et][k0] = *(const short8*)((const char*)xbf +
                              (base + (((32 * k0 + 16 * lh)) ^ sw)));
    }

    // b2 per-lane values (C-init for GEMM2)
    const float bv[2][2] = { { b2[l31], b2[32 + l31] },
                             { b2[64 + l31], b2[96 + l31] } };

    float psum0 = 0.f, psum1 = 0.f;   // per-lane agg partials, h2 = l31 / l31+32

    #pragma unroll
    for (int i = 0; i < 2; ++i) {
        short8 a2f[2][4];
        #pragma unroll
        for (int et = 0; et < 2; ++et) {
            // GEMM1 (swapped): acc1[ht] = q + W1T @ xsT
            f32x16 acc1[2];
            #pragma unroll
            for (int ht = 0; ht < 2; ++ht) {
                f32x16 a;
                #pragma unroll
                for (int qd = 0; qd < 4; ++qd) {
                    float4 qq = *(const float4*)(&qrow[i][32 * ht + 8 * qd + 4 * lh]);
                    a[4 * qd] = qq.x; a[4 * qd + 1] = qq.y;
                    a[4 * qd + 2] = qq.z; a[4 * qd + 3] = qq.w;
                }
                #pragma unroll
                for (int k0 = 0; k0 < 4; ++k0)
                    a = __builtin_amdgcn_mfma_f32_32x32x16_bf16(a1f[ht][k0],
                                                                b1f[et][k0], a, 0, 0, 0);
                acc1[ht] = a;
            }
            // relu + repack (h-in-regs -> k-elements of A2) via cvt_pk + permlane32_swap
            #pragma unroll
            for (int k0 = 0; k0 < 4; ++k0) {
                const int ht = k0 >> 1;
                const int qa = 2 * (k0 & 1), qb = qa + 1;
                unsigned a0 = pk2(fmaxf(acc1[ht][4 * qa], 0.f),
                                  fmaxf(acc1[ht][4 * qa + 1], 0.f));
                unsigned a1 = pk2(fmaxf(acc1[ht][4 * qa + 2], 0.f),
                                  fmaxf(acc1[ht][4 * qa + 3], 0.f));
                unsigned b0 = pk2(fmaxf(acc1[ht][4 * qb], 0.f),
                                  fmaxf(acc1[ht][4 * qb + 1], 0.f));
                unsigned b1w = pk2(fmaxf(acc1[ht][4 * qb + 2], 0.f),
                                   fmaxf(acc1[ht][4 * qb + 3], 0.f));
                pl32swap(a0, b0);
                pl32swap(a1, b1w);
                u32x4 fw = { a0, a1, b0, b1w };
                a2f[et][k0] = __builtin_bit_cast(short8, fw);
            }
        }

        if (i == 0) loadA1(W1 + 8192, l31, lh, a1f);   // prefetch type-1 W1 frags

        // GEMM2 + epilogue per edge-tile
        #pragma unroll
        for (int et = 0; et < 2; ++et) {
            f32x16 acc20, acc21;
            #pragma unroll
            for (int e = 0; e < 16; ++e) { acc20[e] = bv[i][0]; acc21[e] = bv[i][1]; }
            #pragma unroll
            for (int k0 = 0; k0 < 4; ++k0) {
                const short8 B0 = *(const short8*)(W2l + ((i * 8 + k0) * 64 + lane) * 8);
                const short8 B1 = *(const short8*)(W2l + ((i * 8 + 4 + k0) * 64 + lane) * 8);
                acc20 = __builtin_amdgcn_mfma_f32_32x32x16_bf16(a2f[et][k0], B0, acc20, 0, 0, 0);
                acc21 = __builtin_amdgcn_mfma_f32_32x32x16_bf16(a2f[et][k0], B1, acc21, 0, 0, 0);
            }
            #pragma unroll
            for (int qd = 0; qd < 4; ++qd) {
                float4 rq = *(const float4*)(&rt2[i][64 * w + 32 * et + 8 * qd + 4 * lh]);
                #pragma unroll
                for (int m = 0; m < 4; ++m) {
                    psum0 += fmaxf(acc20[4 * qd + m], 0.f) * rq[m];
                    psum1 += fmaxf(acc21[4 * qd + m], 0.f) * rq[m];
                }
            }
        }
    }

    // ---- reduce: lane-halves, then waves ----
    psum0 += __shfl_xor(psum0, 32, 64);
    psum1 += __shfl_xor(psum1, 32, 64);
    if (lh == 0) {
        red[w][l31]      = psum0;
        red[w][l31 + 32] = psum1;
    }
    __syncthreads();
    if (t < 64) aggl[t] = red[0][t] + red[1][t] + red[2][t] + red[3][t];
    __syncthreads();

    // ---- output MLP layer 1: aug(128) @ Wo1(128x64) ----
    {
        const float* src = (w < 2) ? (xl + w * 32) : (aggl + (w - 2) * 32);
        const float* Wp  = Wo1 + (w * 32) * 64 + lane;
        float s = 0.f;
        #pragma unroll 8
        for (int jj = 0; jj < 32; ++jj) s = fmaf(src[jj], Wp[jj * 64], s);
        red[w][lane] = s;
    }
    __syncthreads();
    if (t < 64)
        predl[t] = fmaxf(red[0][t] + red[1][t] + red[2][t] + red[3][t] + bo1[t], 0.f);
    __syncthreads();

    // ---- output MLP layer 2 + residual ----
    {
        const float* Wp = Wo2 + (w * 16) * 64 + lane;
        float s = 0.f;
        #pragma unroll
        for (int jj = 0; jj < 16; ++jj) s = fmaf(predl[w * 16 + jj], Wp[jj * 64], s);
        red[w][lane] = s;
    }
    __syncthreads();
    if (t < 64)
        out[((size_t)b * NB + r) * 64 + t] =
            xl[t] + fmaxf(red[0][t] + red[1][t] + red[2][t] + red[3][t] + bo2[t], 0.f);
}

// ---------------------------------------------------------------------------
extern "C" void kernel_launch(void* const* d_in, const int* in_sizes, int n_in,
                              void* d_out, int out_size, void* d_ws, size_t ws_size,
                              hipStream_t stream) {
    (void)in_sizes; (void)n_in; (void)out_size; (void)d_ws; (void)ws_size;

    const float* x    = (const float*)d_in[0];
    const float* rt   = (const float*)d_in[1];
    // d_in[2] = rel_rec, d_in[3] = rel_send: dense all-pairs one-hot, unused
    const float* W1   = (const float*)d_in[4];
    const float* b1   = (const float*)d_in[5];
    const float* W2   = (const float*)d_in[6];
    const float* b2   = (const float*)d_in[7];
    const float* Wo1  = (const float*)d_in[8];
    const float* bo1  = (const float*)d_in[9];
    const float* Wo2  = (const float*)d_in[10];
    const float* bo2  = (const float*)d_in[11];
    float* out = (float*)d_out;

    fused_kernel<<<BATCH * NB, 256, 0, stream>>>(x, rt, W1, b1, W2, b2,
                                                 Wo1, bo1, Wo2, bo2, out);
}